// Round 2
// baseline (70.435 us; speedup 1.0000x reference)
//
#include <hip/hip_runtime.h>

#define BB 4
#define MM 128
#define LL 512
#define DD 768
#define NEGF (-1e30f)

struct F3 { float x, y, z; };

// Cold-miss MLP version. Every benchmark iteration starts L3-flushed (the
// harness's 256 MB fill), so all loads are cold; the previous 8-row ping-pong
// sustained only ~8 loads in flight per wave -> 5 serial cold round-trips.
// Here: 4 mask + 24 h-row loads issue UPFRONT (28-deep vmcnt pipe), rows are
// consumed row-major (row i dead after use -> compiler emits per-row
// vmcnt(N) streaming waits), last 8 rows issue after the first 8 retire.
// Compute is a wave-uniform scalar branch per (m,row): wbits live in SGPRs
// (readfirstlane'd ballots), masked rows are skipped entirely. Bit-exact:
// h + (-1e30) == -1e30 for |h|<7e22, which is the max-identity with acc
// init -1e30; all-masked case gives -1e30 in both.
// 16 waves (1024 thr) x 32 rows = full L in-block; grid 256 = 1 block/CU.
__global__ __launch_bounds__(1024, 4) void mention_max_kernel(
    const float* __restrict__ h, const int* __restrict__ mask,
    float* __restrict__ out)
{
    const int lane = threadIdx.x & 63;
    const int wave = threadIdx.x >> 6;   // 0..15
    const int dch  = blockIdx.x;         // 0..3
    const int mch  = blockIdx.y;         // 0..15
    const int b    = blockIdx.z;         // 0..3

    const int d0 = dch * 192 + lane * 3;
    const int m0 = mch * 8;
    const int l0 = wave * 32;

    // 1) mask loads first (oldest vmcnt slots -> ballots wait only on these).
    //    lanes 0..31 cover mention m0+2p, lanes 32..63 cover m0+2p+1.
    const int half = lane >> 5;
    const int lrow = lane & 31;
    const int* mp = mask + ((size_t)(b * MM + m0)) * LL + l0 + lrow;
    int mv0 = mp[(0 + half) * LL];
    int mv1 = mp[(2 + half) * LL];
    int mv2 = mp[(4 + half) * LL];
    int mv3 = mp[(6 + half) * LL];

    // 2) 24 of 32 h rows issued upfront: one cold-miss latency for the bulk
    //    of the stream instead of one per 8-row batch.
    const F3* hp = (const F3*)(h + ((size_t)(b * LL + l0)) * DD + d0);
    F3 ra[24];
#pragma unroll
    for (int i = 0; i < 24; ++i) ra[i] = hp[(size_t)i * (DD / 3)];

    // 3) ballots -> SGPR bit masks (readfirstlane forces scalar regs so the
    //    per-row test below compiles to s_bitcmp + s_cbranch, no divergence).
    unsigned wbits[8];
    { unsigned long long bl = __ballot(mv0 != 0);
      wbits[0] = __builtin_amdgcn_readfirstlane((unsigned)bl);
      wbits[1] = __builtin_amdgcn_readfirstlane((unsigned)(bl >> 32)); }
    { unsigned long long bl = __ballot(mv1 != 0);
      wbits[2] = __builtin_amdgcn_readfirstlane((unsigned)bl);
      wbits[3] = __builtin_amdgcn_readfirstlane((unsigned)(bl >> 32)); }
    { unsigned long long bl = __ballot(mv2 != 0);
      wbits[4] = __builtin_amdgcn_readfirstlane((unsigned)bl);
      wbits[5] = __builtin_amdgcn_readfirstlane((unsigned)(bl >> 32)); }
    { unsigned long long bl = __ballot(mv3 != 0);
      wbits[6] = __builtin_amdgcn_readfirstlane((unsigned)bl);
      wbits[7] = __builtin_amdgcn_readfirstlane((unsigned)(bl >> 32)); }

    F3 acc[8];
#pragma unroll
    for (int m = 0; m < 8; ++m) { acc[m].x = NEGF; acc[m].y = NEGF; acc[m].z = NEGF; }

    // Uniform-branch row update: skip masked rows entirely (~2x VALU cut at
    // 50% mask density vs add+max, 4x vs cndmask chains).
#define ROWUPD(R, I)                                                          \
    _Pragma("unroll")                                                         \
    for (int m = 0; m < 8; ++m) {                                             \
        if ((wbits[m] >> (I)) & 1u) {                                         \
            acc[m].x = fmaxf(acc[m].x, (R).x);                                \
            acc[m].y = fmaxf(acc[m].y, (R).y);                                \
            acc[m].z = fmaxf(acc[m].z, (R).z);                                \
        }                                                                     \
    }

    // 4) stream-consume rows 0..7 (frees 24 VGPRs) ...
#pragma unroll
    for (int i = 0; i < 8; ++i) { ROWUPD(ra[i], i) }

    // ... issue the last 8 rows into the freed budget ...
    F3 rb[8];
#pragma unroll
    for (int i = 0; i < 8; ++i) rb[i] = hp[(size_t)(i + 24) * (DD / 3)];

    // ... and consume the rest as it arrives.
#pragma unroll
    for (int i = 8; i < 24; ++i) { ROWUPD(ra[i], i) }
#pragma unroll
    for (int i = 0; i < 8; ++i) { ROWUPD(rb[i], i + 24) }
#undef ROWUPD

    // 5) two-stage 16-wave reduce in 48 KB LDS (component-split, conflict-free).
    __shared__ float red[8][8][3][64];
    if (wave >= 8) {
#pragma unroll
        for (int m = 0; m < 8; ++m) {
            red[wave - 8][m][0][lane] = acc[m].x;
            red[wave - 8][m][1][lane] = acc[m].y;
            red[wave - 8][m][2][lane] = acc[m].z;
        }
    }
    __syncthreads();
    if (wave < 8) {
#pragma unroll
        for (int m = 0; m < 8; ++m) {
            red[wave][m][0][lane] = fmaxf(acc[m].x, red[wave][m][0][lane]);
            red[wave][m][1][lane] = fmaxf(acc[m].y, red[wave][m][1][lane]);
            red[wave][m][2][lane] = fmaxf(acc[m].z, red[wave][m][2][lane]);
        }
    }
    __syncthreads();

    // 6) final: 512 threads -> 8 m x 64 lanes, one float3 output each.
    if (threadIdx.x < 512) {
        const int m  = (int)(threadIdx.x >> 6);
        const int ln = (int)(threadIdx.x & 63);
        float vx = red[0][m][0][ln];
        float vy = red[0][m][1][ln];
        float vz = red[0][m][2][ln];
#pragma unroll
        for (int w = 1; w < 8; ++w) {
            vx = fmaxf(vx, red[w][m][0][ln]);
            vy = fmaxf(vy, red[w][m][1][ln]);
            vz = fmaxf(vz, red[w][m][2][ln]);
        }
        float* op = out + ((size_t)(b * MM + m0 + m)) * DD + dch * 192 + ln * 3;
        op[0] = vx;
        op[1] = vy;
        op[2] = vz;
    }
}

extern "C" void kernel_launch(void* const* d_in, const int* in_sizes, int n_in,
                              void* d_out, int out_size, void* d_ws, size_t ws_size,
                              hipStream_t stream) {
    const float* h    = (const float*)d_in[0];
    const int*   mask = (const int*)d_in[1];
    float*       out  = (float*)d_out;
    dim3 grid(DD / 192, MM / 8, BB);
    mention_max_kernel<<<grid, dim3(1024), 0, stream>>>(h, mask, out);
}